// Round 4
// baseline (79.336 us; speedup 1.0000x reference)
//
#include <hip/hip_runtime.h>
#include <cmath>

#define NCLS 80

// cells per level: 32*3*g*g for g in {52,26,13}
#define CELL0 259584
#define CELL1 64896
#define CELL2 16224
#define CELLT (CELL0 + CELL1 + CELL2)   // 340704

#define NTGT_BLOCKS 720                 // 23040 entries / 32 entries per block
#define NOBJ_BLOCKS ((CELLT + 255) / 256)  // 1331

// ws float layout:
//  [0..15]                                   header: [12]=done-counter (uint), rest scratch
//  [TOBJ_OFF .. TOBJ_OFF+CELLT)              tobj (zeroed each call by k_zero)
//  [PART_OFF .. PART_OFF+NTGT_BLOCKS*4)      per-block {lbox, cls, nvalid, pad}
//  [OPART_OFF .. OPART_OFF+NOBJ_BLOCKS*4)    per-block {obj0, obj1, obj2, pad}
#define TOBJ_OFF 16
#define PART_OFF (TOBJ_OFF + CELLT)
#define OPART_OFF (PART_OFF + NTGT_BLOCKS * 4)
#define CNT_IDX 12

#define ZERO_F4 (CELLT / 4)             // 85176 (CELLT % 4 == 0)
#define NZERO_BLOCKS ((ZERO_F4 + 255) / 256)

__device__ __constant__ float c_anch[3][3][2] = {
    {{1.25f, 1.625f}, {2.0f, 3.75f}, {4.125f, 2.875f}},
    {{1.875f, 3.8125f}, {3.875f, 2.8125f}, {3.6875f, 7.4375f}},
    {{3.625f, 2.8125f}, {4.875f, 6.1875f}, {11.65625f, 10.1875f}}};
__device__ __constant__ float c_offx[5] = {0.f, 0.5f, 0.f, -0.5f, 0.f};
__device__ __constant__ float c_offy[5] = {0.f, 0.f, 0.5f, 0.f, -0.5f};

__device__ __forceinline__ float bce(float x, float y) {
    return fmaxf(x, 0.f) - x * y + log1pf(expf(-fabsf(x)));
}

// Zero tobj + header (incl. done-counter).
__global__ __launch_bounds__(256) void k_zero(float* __restrict__ ws) {
    const int i = blockIdx.x * 256 + threadIdx.x;
    if (blockIdx.x == 0 && threadIdx.x < 16) ws[threadIdx.x] = 0.f;
    if (i < ZERO_F4) {
        float4 z;
        z.x = 0.f; z.y = 0.f; z.z = 0.f; z.w = 0.f;
        ((float4*)(ws + TOBJ_OFF))[i] = z;
    }
}

// 8-lane group per entry: 8 entries/wave, 32 entries/block -> 720 blocks.
// Scalar CIoU math redundant across 8 lanes (free in SIMT); 85-elem row split
// across the 8 lanes (10-11 elems each) for the class BCE.
__global__ __launch_bounds__(256) void k_targets(const float* __restrict__ p0,
                                                 const float* __restrict__ p1,
                                                 const float* __restrict__ p2,
                                                 const float* __restrict__ tgt,
                                                 float* __restrict__ ws) {
    const int lane = threadIdx.x & 63;
    const int wid = threadIdx.x >> 6;
    const int g = lane & 7;        // lane within group
    const int grp = lane >> 3;     // group within wave (0..7)
    const int gid = blockIdx.x * 32 + wid * 8 + grp;  // entry 0..23039

    const int lev = gid / 7680;    // block-uniform (240 blocks per level)
    const int m = gid - lev * 7680;
    const int o = m / 1536;        // wave-uniform (1536 % 8 == 0)
    const int n = m - o * 1536;
    const int a = n >> 9;          // anchor, wave-uniform
    const int j = n & 511;         // target index, per-group

    const int gsz = (lev == 0) ? 52 : ((lev == 1) ? 26 : 13);
    const float* p = (lev == 0) ? p0 : ((lev == 1) ? p1 : p2);
    const int toff = (lev == 0) ? 0 : ((lev == 1) ? CELL0 : (CELL0 + CELL1));

    // target row (8 lanes of a group read the same addresses -> broadcast)
    const float2 t01 = *(const float2*)(tgt + j * 6 + 0);
    const float2 t23 = *(const float2*)(tgt + j * 6 + 2);
    const float2 t45 = *(const float2*)(tgt + j * 6 + 4);
    const float img = t01.x, cls = t01.y;
    const float x1 = t23.x, y1 = t23.y, x2 = t45.x, y2 = t45.y;
    const float w = (float)gsz, h = (float)gsz;
    const float cx = (x1 + x2) * 0.5f, cy = (y1 + y2) * 0.5f;
    const float tw = x2 - x1, th = y2 - y1;
    const float gx = cx * w, gy = cy * h, gw = tw * w, gh = th * h;

    // anchor-ratio + offset masks
    const float ax = c_anch[lev][a][0], ay = c_anch[lev][a][1];
    const float rx = gw / ax, ry = gh / ay;
    const float mr = fmaxf(fmaxf(rx, 1.0f / rx), fmaxf(ry, 1.0f / ry));
    bool valid = (mr < 4.0f);
    if (o == 1)
        valid = valid && (gx - floorf(gx) < 0.5f) && (gx > 1.0f);
    else if (o == 2)
        valid = valid && (gy - floorf(gy) < 0.5f) && (gy > 1.0f);
    else if (o == 3) {
        const float gxi = w - gx;
        valid = valid && (gxi - floorf(gxi) < 0.5f) && (gxi > 1.0f);
    } else if (o == 4) {
        const float gyi = h - gy;
        valid = valid && (gyi - floorf(gyi) < 0.5f) && (gyi > 1.0f);
    }

    float lbox_c = 0.f, cls_c = 0.f, cnt_c = 0.f;

    if (valid) {
        const float gijx = floorf(gx - c_offx[o]);
        const float gijy = floorf(gy - c_offy[o]);
        int gi = (int)gijx;
        gi = min(max(gi, 0), gsz - 1);
        int gj = (int)gijy;
        gj = min(max(gj, 0), gsz - 1);
        const int b = (int)img;
        const int c = (int)cls;
        const int cell = ((b * 3 + a) * gsz + gj) * gsz + gi;
        const long base = (long)cell * 85;

        // row split: lane g covers elems {g+8k}; class BCE for elems >= 5
        float x0 = 0.f, s = 0.f;
#pragma unroll
        for (int k = 0; k < 11; ++k) {
            const int elem = g + 8 * k;
            if (elem < 85) {
                const float x = p[base + elem];
                if (k == 0) x0 = x;
                if (elem >= 5) s += bce(x, (elem - 5 == c) ? 0.95f : 0.05f);
            }
        }
        cls_c = s;

        // broadcast box logits (elems 0..3 live in lanes g=0..3 of this group, k=0)
        const int gb = lane & 56;
        const float t0 = __shfl(x0, gb + 0);
        const float t1 = __shfl(x0, gb + 1);
        const float t2 = __shfl(x0, gb + 2);
        const float t3 = __shfl(x0, gb + 3);

        const float sx = 1.f / (1.f + expf(-t0));
        const float sy = 1.f / (1.f + expf(-t1));
        const float sw = 1.f / (1.f + expf(-t2));
        const float sh = 1.f / (1.f + expf(-t3));
        const float pxc = sx * 2.f - 0.5f;
        const float pyc = sy * 2.f - 0.5f;
        const float pw = (sw * 2.f) * (sw * 2.f) * ax;
        const float ph = (sh * 2.f) * (sh * 2.f) * ay;

        const float tbx = gx - gijx, tby = gy - gijy, tbw = gw, tbh = gh;

        const float b1x1 = pxc - pw * 0.5f, b1x2 = pxc + pw * 0.5f;
        const float b1y1 = pyc - ph * 0.5f, b1y2 = pyc + ph * 0.5f;
        const float b2x1 = tbx - tbw * 0.5f, b2x2 = tbx + tbw * 0.5f;
        const float b2y1 = tby - tbh * 0.5f, b2y2 = tby + tbh * 0.5f;
        float iw = fminf(b1x2, b2x2) - fmaxf(b1x1, b2x1);
        iw = fmaxf(iw, 0.f);
        float ih = fminf(b1y2, b2y2) - fmaxf(b1y1, b2y1);
        ih = fmaxf(ih, 0.f);
        const float inter = iw * ih;
        const float uni = pw * ph + tbw * tbh - inter + 1e-7f;
        const float iou = inter / uni;
        const float cw = fmaxf(b1x2, b2x2) - fminf(b1x1, b2x1);
        const float ch = fmaxf(b1y2, b2y2) - fminf(b1y1, b2y1);
        const float c2 = cw * cw + ch * ch + 1e-7f;
        const float dx = b2x1 + b2x2 - b1x1 - b1x2;
        const float dy = b2y1 + b2y2 - b1y1 - b1y2;
        const float rho2 = (dx * dx + dy * dy) * 0.25f;
        const float dv = atanf(tbw / tbh) - atanf(pw / ph);
        const float v = 0.40528473f * dv * dv;  // 4/pi^2
        const float alpha = v / (v - iou + 1.0000001f);
        const float ciou = iou - (rho2 / c2 + v * alpha);

        if (g == 0) {
            lbox_c = 1.f - ciou;
            cnt_c = 1.f;
            const float score = fmaxf(ciou, 0.f);
            if (score > 0.f) {
                unsigned int* tobj = (unsigned int*)(ws + TOBJ_OFF + toff);
                atomicMax(tobj + cell, __float_as_uint(score));
            }
        }
    }

    // wave-wide reduce (lbox/cnt only from group lane 0; cls is per-lane-distinct)
#pragma unroll
    for (int msk = 1; msk < 64; msk <<= 1) {
        lbox_c += __shfl_xor(lbox_c, msk);
        cls_c += __shfl_xor(cls_c, msk);
        cnt_c += __shfl_xor(cnt_c, msk);
    }
    __shared__ float sb[4], sc[4], sn[4];
    if (lane == 0) {
        sb[wid] = lbox_c;
        sc[wid] = cls_c;
        sn[wid] = cnt_c;
    }
    __syncthreads();
    if (threadIdx.x == 0) {
        float* slot = ws + PART_OFF + blockIdx.x * 4;
        slot[0] = sb[0] + sb[1] + sb[2] + sb[3];
        slot[1] = sc[0] + sc[1] + sc[2] + sc[3];
        slot[2] = sn[0] + sn[1] + sn[2] + sn[3];
    }
}

// Obj scan + per-block partials; the LAST block (device-scope counter) reduces
// all partials (targets + obj) and writes the 4 outputs. Saves one dispatch.
__global__ __launch_bounds__(256) void k_obj_final(const float* __restrict__ p0,
                                                   const float* __restrict__ p1,
                                                   const float* __restrict__ p2,
                                                   float* __restrict__ ws,
                                                   float* __restrict__ out) {
    const int idx = blockIdx.x * 256 + threadIdx.x;
    float v0 = 0.f, v1 = 0.f, v2 = 0.f;
    if (idx < CELLT) {
        const float* p;
        int cell, toff, lev;
        if (idx < CELL0) {
            lev = 0; cell = idx; p = p0; toff = 0;
        } else if (idx < CELL0 + CELL1) {
            lev = 1; cell = idx - CELL0; p = p1; toff = CELL0;
        } else {
            lev = 2; cell = idx - (CELL0 + CELL1); p = p2; toff = CELL0 + CELL1;
        }
        const float x = p[(long)cell * 85 + 4];
        const float t = ws[TOBJ_OFF + toff + cell];
        const float b = fmaxf(x, 0.f) - x * t + log1pf(expf(-fabsf(x)));
        if (lev == 0) v0 = b;
        else if (lev == 1) v1 = b;
        else v2 = b;
    }
#pragma unroll
    for (int msk = 32; msk; msk >>= 1) {
        v0 += __shfl_xor(v0, msk);
        v1 += __shfl_xor(v1, msk);
        v2 += __shfl_xor(v2, msk);
    }
    __shared__ float s0[4], s1[4], s2[4];
    const int wid = threadIdx.x >> 6, lane = threadIdx.x & 63;
    if (lane == 0) {
        s0[wid] = v0;
        s1[wid] = v1;
        s2[wid] = v2;
    }
    __syncthreads();

    __shared__ unsigned int is_last;
    if (threadIdx.x == 0) {
        float* slot = ws + OPART_OFF + blockIdx.x * 4;
        slot[0] = s0[0] + s0[1] + s0[2] + s0[3];
        slot[1] = s1[0] + s1[1] + s1[2] + s1[3];
        slot[2] = s2[0] + s2[1] + s2[2] + s2[3];
        __threadfence();  // release partials to device scope
        const unsigned int old = __hip_atomic_fetch_add(
            (unsigned int*)ws + CNT_IDX, 1u, __ATOMIC_ACQ_REL, __HIP_MEMORY_SCOPE_AGENT);
        is_last = (old == (unsigned int)(NOBJ_BLOCKS - 1)) ? 1u : 0u;
    }
    __syncthreads();
    if (!is_last) return;

    // ---- final reduction (one block; acquire above makes partials visible) ----
    float acc[12];
#pragma unroll
    for (int q = 0; q < 12; ++q) acc[q] = 0.f;

    for (int i = threadIdx.x; i < NTGT_BLOCKS; i += 256) {
        const int lev = i / 240;  // 240 k_targets blocks per level
        const float* slot = ws + PART_OFF + i * 4;
        acc[lev] += slot[0];
        acc[3 + lev] += slot[1];
        acc[6 + lev] += slot[2];
    }
    for (int i = threadIdx.x; i < NOBJ_BLOCKS; i += 256) {
        const float* slot = ws + OPART_OFF + i * 4;
        acc[9] += slot[0];
        acc[10] += slot[1];
        acc[11] += slot[2];
    }
#pragma unroll
    for (int q = 0; q < 12; ++q)
        for (int msk = 32; msk; msk >>= 1) acc[q] += __shfl_xor(acc[q], msk);

    __shared__ float sh[4][12];
    if (lane == 0)
#pragma unroll
        for (int q = 0; q < 12; ++q) sh[wid][q] = acc[q];
    __syncthreads();

    if (threadIdx.x == 0) {
        float lbox = 0.f, lobj = 0.f, lcls = 0.f;
        const float bal[3] = {4.0f, 1.0f, 0.4f};
        const float ncell[3] = {(float)CELL0, (float)CELL1, (float)CELL2};
        for (int l = 0; l < 3; ++l) {
            const float sbv = sh[0][l] + sh[1][l] + sh[2][l] + sh[3][l];
            const float scv = sh[0][3 + l] + sh[1][3 + l] + sh[2][3 + l] + sh[3][3 + l];
            const float snv = sh[0][6 + l] + sh[1][6 + l] + sh[2][6 + l] + sh[3][6 + l];
            const float sov = sh[0][9 + l] + sh[1][9 + l] + sh[2][9 + l] + sh[3][9 + l];
            const float nv = fmaxf(snv, 1.0f);
            lbox += sbv / nv;
            lcls += scv / (nv * (float)NCLS);
            lobj += sov / ncell[l] * bal[l];
        }
        lbox *= 0.05f;
        lcls *= 0.5f;
        const float total = (lbox + lobj + lcls) * 32.0f;
        out[0] = total;
        out[1] = lbox;
        out[2] = lobj;
        out[3] = lcls;
    }
}

extern "C" void kernel_launch(void* const* d_in, const int* in_sizes, int n_in,
                              void* d_out, int out_size, void* d_ws, size_t ws_size,
                              hipStream_t stream) {
    const float* p0 = (const float*)d_in[0];
    const float* p1 = (const float*)d_in[1];
    const float* p2 = (const float*)d_in[2];
    const float* tgt = (const float*)d_in[3];
    float* ws = (float*)d_ws;
    float* out = (float*)d_out;

    k_zero<<<NZERO_BLOCKS, 256, 0, stream>>>(ws);
    k_targets<<<NTGT_BLOCKS, 256, 0, stream>>>(p0, p1, p2, tgt, ws);
    k_obj_final<<<NOBJ_BLOCKS, 256, 0, stream>>>(p0, p1, p2, ws, out);
}

// Round 5
// 52.476 us; speedup vs baseline: 1.5118x; 1.5118x over previous
//
#include <hip/hip_runtime.h>
#include <cmath>

#define NCLS 80

// cells per level: 32*3*g*g for g in {52,26,13}
#define CELL0 259584
#define CELL1 64896
#define CELL2 16224
#define CELLT (CELL0 + CELL1 + CELL2)   // 340704

#define NTGT_BLOCKS 720                 // 23040 entries / 32 entries per block
#define NTGT_THREADS (NTGT_BLOCKS * 256)
#define NCORR_BLOCKS 16

// ws float layout:
//  [0..15]                                   header: [12]=done-counter (uint)
//  [TOBJ_OFF .. TOBJ_OFF+CELLT)              tobj (zeroed each call by k_zero)
//  [PART_OFF .. PART_OFF+NTGT_BLOCKS*8)      per-block {lbox, cls, nvalid, obj0, obj1, obj2, pad, pad}
//  [CORR_OFF .. CORR_OFF+NCORR_BLOCKS*4)     per-block {xt0, xt1, xt2, pad}
#define TOBJ_OFF 16
#define PART_OFF (TOBJ_OFF + CELLT)
#define CORR_OFF (PART_OFF + NTGT_BLOCKS * 8)
#define CNT_IDX 12

#define ZERO_F4 (CELLT / 4)             // 85176 (CELLT % 4 == 0)
#define NZERO_BLOCKS ((ZERO_F4 + 255) / 256)

__device__ __constant__ float c_anch[3][3][2] = {
    {{1.25f, 1.625f}, {2.0f, 3.75f}, {4.125f, 2.875f}},
    {{1.875f, 3.8125f}, {3.875f, 2.8125f}, {3.6875f, 7.4375f}},
    {{3.625f, 2.8125f}, {4.875f, 6.1875f}, {11.65625f, 10.1875f}}};
__device__ __constant__ float c_offx[5] = {0.f, 0.5f, 0.f, -0.5f, 0.f};
__device__ __constant__ float c_offy[5] = {0.f, 0.f, 0.5f, 0.f, -0.5f};

__device__ __forceinline__ float bce(float x, float y) {
    return fmaxf(x, 0.f) - x * y + log1pf(expf(-fabsf(x)));
}
__device__ __forceinline__ float softplus_bce0(float x) {  // bce(x, 0)
    return fmaxf(x, 0.f) + log1pf(expf(-fabsf(x)));
}

// Zero tobj + header (incl. done-counter).
__global__ __launch_bounds__(256) void k_zero(float* __restrict__ ws) {
    const int i = blockIdx.x * 256 + threadIdx.x;
    if (blockIdx.x == 0 && threadIdx.x < 16) ws[threadIdx.x] = 0.f;
    if (i < ZERO_F4) {
        float4 z;
        z.x = 0.f; z.y = 0.f; z.z = 0.f; z.w = 0.f;
        ((float4*)(ws + TOBJ_OFF))[i] = z;
    }
}

// Phase A: 8-lane group per entry (8 entries/wave, 32/block, 720 blocks) -> box/cls/valid + tobj scatter.
// Phase B (fused, independent of tobj): grid-stride sum of bce(x_obj, 0) over all cells.
// bce(x,t) = bce(x,0) - x*t, so the t-dependent part is handled later by k_corr_final.
__global__ __launch_bounds__(256) void k_targets_plus(const float* __restrict__ p0,
                                                      const float* __restrict__ p1,
                                                      const float* __restrict__ p2,
                                                      const float* __restrict__ tgt,
                                                      float* __restrict__ ws) {
    const int lane = threadIdx.x & 63;
    const int wid = threadIdx.x >> 6;
    const int g = lane & 7;
    const int grp = lane >> 3;
    const int gid = blockIdx.x * 32 + wid * 8 + grp;  // entry 0..23039

    const int lev = gid / 7680;
    const int m = gid - lev * 7680;
    const int o = m / 1536;
    const int n = m - o * 1536;
    const int a = n >> 9;
    const int j = n & 511;

    const int gsz = (lev == 0) ? 52 : ((lev == 1) ? 26 : 13);
    const float* p = (lev == 0) ? p0 : ((lev == 1) ? p1 : p2);
    const int toff = (lev == 0) ? 0 : ((lev == 1) ? CELL0 : (CELL0 + CELL1));

    const float2 t01 = *(const float2*)(tgt + j * 6 + 0);
    const float2 t23 = *(const float2*)(tgt + j * 6 + 2);
    const float2 t45 = *(const float2*)(tgt + j * 6 + 4);
    const float img = t01.x, cls = t01.y;
    const float x1 = t23.x, y1 = t23.y, x2 = t45.x, y2 = t45.y;
    const float w = (float)gsz, h = (float)gsz;
    const float cx = (x1 + x2) * 0.5f, cy = (y1 + y2) * 0.5f;
    const float tw = x2 - x1, th = y2 - y1;
    const float gx = cx * w, gy = cy * h, gw = tw * w, gh = th * h;

    const float ax = c_anch[lev][a][0], ay = c_anch[lev][a][1];
    const float rx = gw / ax, ry = gh / ay;
    const float mr = fmaxf(fmaxf(rx, 1.0f / rx), fmaxf(ry, 1.0f / ry));
    bool valid = (mr < 4.0f);
    if (o == 1)
        valid = valid && (gx - floorf(gx) < 0.5f) && (gx > 1.0f);
    else if (o == 2)
        valid = valid && (gy - floorf(gy) < 0.5f) && (gy > 1.0f);
    else if (o == 3) {
        const float gxi = w - gx;
        valid = valid && (gxi - floorf(gxi) < 0.5f) && (gxi > 1.0f);
    } else if (o == 4) {
        const float gyi = h - gy;
        valid = valid && (gyi - floorf(gyi) < 0.5f) && (gyi > 1.0f);
    }

    float lbox_c = 0.f, cls_c = 0.f, cnt_c = 0.f;

    if (valid) {
        const float gijx = floorf(gx - c_offx[o]);
        const float gijy = floorf(gy - c_offy[o]);
        int gi = (int)gijx;
        gi = min(max(gi, 0), gsz - 1);
        int gj = (int)gijy;
        gj = min(max(gj, 0), gsz - 1);
        const int b = (int)img;
        const int c = (int)cls;
        const int cell = ((b * 3 + a) * gsz + gj) * gsz + gi;
        const long base = (long)cell * 85;

        float x0 = 0.f, s = 0.f;
#pragma unroll
        for (int k = 0; k < 11; ++k) {
            const int elem = g + 8 * k;
            if (elem < 85) {
                const float x = p[base + elem];
                if (k == 0) x0 = x;
                if (elem >= 5) s += bce(x, (elem - 5 == c) ? 0.95f : 0.05f);
            }
        }
        cls_c = s;

        const int gb = lane & 56;
        const float t0 = __shfl(x0, gb + 0);
        const float t1 = __shfl(x0, gb + 1);
        const float t2 = __shfl(x0, gb + 2);
        const float t3 = __shfl(x0, gb + 3);

        const float sx = 1.f / (1.f + expf(-t0));
        const float sy = 1.f / (1.f + expf(-t1));
        const float sw = 1.f / (1.f + expf(-t2));
        const float sh = 1.f / (1.f + expf(-t3));
        const float pxc = sx * 2.f - 0.5f;
        const float pyc = sy * 2.f - 0.5f;
        const float pw = (sw * 2.f) * (sw * 2.f) * ax;
        const float ph = (sh * 2.f) * (sh * 2.f) * ay;

        const float tbx = gx - gijx, tby = gy - gijy, tbw = gw, tbh = gh;

        const float b1x1 = pxc - pw * 0.5f, b1x2 = pxc + pw * 0.5f;
        const float b1y1 = pyc - ph * 0.5f, b1y2 = pyc + ph * 0.5f;
        const float b2x1 = tbx - tbw * 0.5f, b2x2 = tbx + tbw * 0.5f;
        const float b2y1 = tby - tbh * 0.5f, b2y2 = tby + tbh * 0.5f;
        float iw = fminf(b1x2, b2x2) - fmaxf(b1x1, b2x1);
        iw = fmaxf(iw, 0.f);
        float ih = fminf(b1y2, b2y2) - fmaxf(b1y1, b2y1);
        ih = fmaxf(ih, 0.f);
        const float inter = iw * ih;
        const float uni = pw * ph + tbw * tbh - inter + 1e-7f;
        const float iou = inter / uni;
        const float cw = fmaxf(b1x2, b2x2) - fminf(b1x1, b2x1);
        const float ch = fmaxf(b1y2, b2y2) - fminf(b1y1, b2y1);
        const float c2 = cw * cw + ch * ch + 1e-7f;
        const float dx = b2x1 + b2x2 - b1x1 - b1x2;
        const float dy = b2y1 + b2y2 - b1y1 - b1y2;
        const float rho2 = (dx * dx + dy * dy) * 0.25f;
        const float dv = atanf(tbw / tbh) - atanf(pw / ph);
        const float v = 0.40528473f * dv * dv;  // 4/pi^2
        const float alpha = v / (v - iou + 1.0000001f);
        const float ciou = iou - (rho2 / c2 + v * alpha);

        if (g == 0) {
            lbox_c = 1.f - ciou;
            cnt_c = 1.f;
            const float score = fmaxf(ciou, 0.f);
            if (score > 0.f) {
                unsigned int* tobj = (unsigned int*)(ws + TOBJ_OFF + toff);
                atomicMax(tobj + cell, __float_as_uint(score));
            }
        }
    }

    // Phase B: softplus(obj) over all cells, grid-stride (2 iterations max).
    float v0 = 0.f, v1 = 0.f, v2 = 0.f;
    for (int i = blockIdx.x * 256 + threadIdx.x; i < CELLT; i += NTGT_THREADS) {
        const float* p2_;
        int cell2;
        float* dst;
        if (i < CELL0) {
            p2_ = p0; cell2 = i; dst = &v0;
        } else if (i < CELL0 + CELL1) {
            p2_ = p1; cell2 = i - CELL0; dst = &v1;
        } else {
            p2_ = p2; cell2 = i - (CELL0 + CELL1); dst = &v2;
        }
        *dst += softplus_bce0(p2_[(long)cell2 * 85 + 4]);
    }

    // wave-wide reduce of 6 values
#pragma unroll
    for (int msk = 1; msk < 64; msk <<= 1) {
        lbox_c += __shfl_xor(lbox_c, msk);
        cls_c += __shfl_xor(cls_c, msk);
        cnt_c += __shfl_xor(cnt_c, msk);
        v0 += __shfl_xor(v0, msk);
        v1 += __shfl_xor(v1, msk);
        v2 += __shfl_xor(v2, msk);
    }
    __shared__ float sh[4][6];
    if (lane == 0) {
        sh[wid][0] = lbox_c; sh[wid][1] = cls_c; sh[wid][2] = cnt_c;
        sh[wid][3] = v0; sh[wid][4] = v1; sh[wid][5] = v2;
    }
    __syncthreads();
    if (threadIdx.x == 0) {
        float* slot = ws + PART_OFF + blockIdx.x * 8;
#pragma unroll
        for (int q = 0; q < 6; ++q)
            slot[q] = sh[0][q] + sh[1][q] + sh[2][q] + sh[3][q];
    }
}

// 16 blocks: scan tobj (float4), gather x_obj for nonzero cells, accumulate xt = sum(x*t);
// last block (16 cheap counter atomics) reduces everything and writes the outputs.
__global__ __launch_bounds__(256) void k_corr_final(const float* __restrict__ p0,
                                                    const float* __restrict__ p1,
                                                    const float* __restrict__ p2,
                                                    float* __restrict__ ws,
                                                    float* __restrict__ out) {
    float xt0 = 0.f, xt1 = 0.f, xt2 = 0.f;
    const float4* tobj4 = (const float4*)(ws + TOBJ_OFF);
    for (int i = blockIdx.x * 256 + threadIdx.x; i < ZERO_F4; i += NCORR_BLOCKS * 256) {
        const float4 t4 = tobj4[i];
        if (t4.x > 0.f || t4.y > 0.f || t4.z > 0.f || t4.w > 0.f) {
            const int gbase = 4 * i;  // all 4 cells share a level (CELL0, CELL1 % 4 == 0)
            const float* p;
            int cb;
            float* dst;
            if (gbase < CELL0) {
                p = p0; cb = gbase; dst = &xt0;
            } else if (gbase < CELL0 + CELL1) {
                p = p1; cb = gbase - CELL0; dst = &xt1;
            } else {
                p = p2; cb = gbase - (CELL0 + CELL1); dst = &xt2;
            }
            float acc = 0.f;
            if (t4.x > 0.f) acc += p[(long)(cb + 0) * 85 + 4] * t4.x;
            if (t4.y > 0.f) acc += p[(long)(cb + 1) * 85 + 4] * t4.y;
            if (t4.z > 0.f) acc += p[(long)(cb + 2) * 85 + 4] * t4.z;
            if (t4.w > 0.f) acc += p[(long)(cb + 3) * 85 + 4] * t4.w;
            *dst += acc;
        }
    }
#pragma unroll
    for (int msk = 1; msk < 64; msk <<= 1) {
        xt0 += __shfl_xor(xt0, msk);
        xt1 += __shfl_xor(xt1, msk);
        xt2 += __shfl_xor(xt2, msk);
    }
    __shared__ float s0[4], s1[4], s2[4];
    const int wid = threadIdx.x >> 6, lane = threadIdx.x & 63;
    if (lane == 0) {
        s0[wid] = xt0; s1[wid] = xt1; s2[wid] = xt2;
    }
    __syncthreads();

    __shared__ unsigned int is_last;
    if (threadIdx.x == 0) {
        float* slot = ws + CORR_OFF + blockIdx.x * 4;
        slot[0] = s0[0] + s0[1] + s0[2] + s0[3];
        slot[1] = s1[0] + s1[1] + s1[2] + s1[3];
        slot[2] = s2[0] + s2[1] + s2[2] + s2[3];
        __threadfence();
        const unsigned int old = __hip_atomic_fetch_add(
            (unsigned int*)ws + CNT_IDX, 1u, __ATOMIC_ACQ_REL, __HIP_MEMORY_SCOPE_AGENT);
        is_last = (old == (unsigned int)(NCORR_BLOCKS - 1)) ? 1u : 0u;
    }
    __syncthreads();
    if (!is_last) return;

    // ---- final reduction ----
    // acc: [0..2]=lbox [3..5]=cls [6..8]=nvalid [9..11]=softplus-obj [12..14]=xt
    float acc[15];
#pragma unroll
    for (int q = 0; q < 15; ++q) acc[q] = 0.f;

    for (int i = threadIdx.x; i < NTGT_BLOCKS; i += 256) {
        const int lev = i / 240;
        const float* slot = ws + PART_OFF + i * 8;
        acc[lev] += slot[0];
        acc[3 + lev] += slot[1];
        acc[6 + lev] += slot[2];
        acc[9] += slot[3];
        acc[10] += slot[4];
        acc[11] += slot[5];
    }
    if (threadIdx.x < NCORR_BLOCKS) {
        const float* slot = ws + CORR_OFF + threadIdx.x * 4;
        acc[12] += slot[0];
        acc[13] += slot[1];
        acc[14] += slot[2];
    }
#pragma unroll
    for (int q = 0; q < 15; ++q)
        for (int msk = 32; msk; msk >>= 1) acc[q] += __shfl_xor(acc[q], msk);

    __shared__ float shf[4][15];
    if (lane == 0)
#pragma unroll
        for (int q = 0; q < 15; ++q) shf[wid][q] = acc[q];
    __syncthreads();

    if (threadIdx.x == 0) {
        float lbox = 0.f, lobj = 0.f, lcls = 0.f;
        const float bal[3] = {4.0f, 1.0f, 0.4f};
        const float ncell[3] = {(float)CELL0, (float)CELL1, (float)CELL2};
        for (int l = 0; l < 3; ++l) {
            const float sbv = shf[0][l] + shf[1][l] + shf[2][l] + shf[3][l];
            const float scv = shf[0][3 + l] + shf[1][3 + l] + shf[2][3 + l] + shf[3][3 + l];
            const float snv = shf[0][6 + l] + shf[1][6 + l] + shf[2][6 + l] + shf[3][6 + l];
            const float sov = shf[0][9 + l] + shf[1][9 + l] + shf[2][9 + l] + shf[3][9 + l];
            const float sxt = shf[0][12 + l] + shf[1][12 + l] + shf[2][12 + l] + shf[3][12 + l];
            const float nv = fmaxf(snv, 1.0f);
            lbox += sbv / nv;
            lcls += scv / (nv * (float)NCLS);
            lobj += (sov - sxt) / ncell[l] * bal[l];  // bce(x,t) = bce(x,0) - x*t
        }
        lbox *= 0.05f;
        lcls *= 0.5f;
        const float total = (lbox + lobj + lcls) * 32.0f;
        out[0] = total;
        out[1] = lbox;
        out[2] = lobj;
        out[3] = lcls;
    }
}

extern "C" void kernel_launch(void* const* d_in, const int* in_sizes, int n_in,
                              void* d_out, int out_size, void* d_ws, size_t ws_size,
                              hipStream_t stream) {
    const float* p0 = (const float*)d_in[0];
    const float* p1 = (const float*)d_in[1];
    const float* p2 = (const float*)d_in[2];
    const float* tgt = (const float*)d_in[3];
    float* ws = (float*)d_ws;
    float* out = (float*)d_out;

    k_zero<<<NZERO_BLOCKS, 256, 0, stream>>>(ws);
    k_targets_plus<<<NTGT_BLOCKS, 256, 0, stream>>>(p0, p1, p2, tgt, ws);
    k_corr_final<<<NCORR_BLOCKS, 256, 0, stream>>>(p0, p1, p2, ws, out);
}

// Round 6
// 52.360 us; speedup vs baseline: 1.5152x; 1.0022x over previous
//
#include <hip/hip_runtime.h>
#include <cmath>

#define NCLS 80

// cells per level: 32*3*g*g for g in {52,26,13}
#define CELL0 259584
#define CELL1 64896
#define CELL2 16224
#define CELLT (CELL0 + CELL1 + CELL2)   // 340704

#define NTGT_BLOCKS 720                 // 23040 entries / 32 entries per block
#define NTGT_THREADS (NTGT_BLOCKS * 256)  // 184320
#define NCORR_BLOCKS 16
#define CORR_THREADS (NCORR_BLOCKS * 256) // 4096

// ws float layout:
//  [0..15]                                   header: [12]=done-counter (uint)
//  [TOBJ_OFF .. TOBJ_OFF+CELLT)              tobj (zeroed each call by k_zero)
//  [PART_OFF .. PART_OFF+NTGT_BLOCKS*8)      per-block {lbox, cls, nvalid, obj0, obj1, obj2, pad, pad}
//  [CORR_OFF .. CORR_OFF+NCORR_BLOCKS*4)     per-block {xt0, xt1, xt2, pad}
#define TOBJ_OFF 16
#define PART_OFF (TOBJ_OFF + CELLT)
#define CORR_OFF (PART_OFF + NTGT_BLOCKS * 8)
#define CNT_IDX 12

#define ZERO_F4 (CELLT / 4)             // 85176 (CELLT % 4 == 0; level bounds are /4-exact too)
#define NZERO_BLOCKS ((ZERO_F4 + 255) / 256)

__device__ __constant__ float c_anch[3][3][2] = {
    {{1.25f, 1.625f}, {2.0f, 3.75f}, {4.125f, 2.875f}},
    {{1.875f, 3.8125f}, {3.875f, 2.8125f}, {3.6875f, 7.4375f}},
    {{3.625f, 2.8125f}, {4.875f, 6.1875f}, {11.65625f, 10.1875f}}};
__device__ __constant__ float c_offx[5] = {0.f, 0.5f, 0.f, -0.5f, 0.f};
__device__ __constant__ float c_offy[5] = {0.f, 0.f, 0.5f, 0.f, -0.5f};

__device__ __forceinline__ float bce(float x, float y) {
    return fmaxf(x, 0.f) - x * y + log1pf(expf(-fabsf(x)));
}
__device__ __forceinline__ float softplus_bce0(float x) {  // bce(x, 0)
    return fmaxf(x, 0.f) + log1pf(expf(-fabsf(x)));
}

// Zero tobj + header (incl. done-counter).
__global__ __launch_bounds__(256) void k_zero(float* __restrict__ ws) {
    const int i = blockIdx.x * 256 + threadIdx.x;
    if (blockIdx.x == 0 && threadIdx.x < 16) ws[threadIdx.x] = 0.f;
    if (i < ZERO_F4) {
        float4 z;
        z.x = 0.f; z.y = 0.f; z.z = 0.f; z.w = 0.f;
        ((float4*)(ws + TOBJ_OFF))[i] = z;
    }
}

// Phase B loads issued FIRST (latency hides under Phase A compute), Phase A = 8-lane
// group per entry, Phase B softplus accumulated into NAMED registers (no pointer-to-local).
__global__ __launch_bounds__(256) void k_targets_plus(const float* __restrict__ p0,
                                                      const float* __restrict__ p1,
                                                      const float* __restrict__ p2,
                                                      const float* __restrict__ tgt,
                                                      float* __restrict__ ws) {
    // ---- Phase B: issue the two strided obj loads up front (independent of Phase A) ----
    const int i0 = blockIdx.x * 256 + threadIdx.x;      // always < CELLT
    const int i1 = i0 + NTGT_THREADS;
    const bool hb = (i1 < CELLT);
    float xa, xbv = 0.f;
    {
        const float* pa;
        long ca;
        if (i0 < CELL0) { pa = p0; ca = i0; }
        else if (i0 < CELL0 + CELL1) { pa = p1; ca = i0 - CELL0; }
        else { pa = p2; ca = i0 - (CELL0 + CELL1); }
        xa = pa[ca * 85 + 4];
        if (hb) {
            const float* pb;
            long cb;
            if (i1 < CELL0) { pb = p0; cb = i1; }
            else if (i1 < CELL0 + CELL1) { pb = p1; cb = i1 - CELL0; }
            else { pb = p2; cb = i1 - (CELL0 + CELL1); }
            xbv = pb[cb * 85 + 4];
        }
    }

    // ---- Phase A: one entry per 8-lane group ----
    const int lane = threadIdx.x & 63;
    const int wid = threadIdx.x >> 6;
    const int g = lane & 7;
    const int grp = lane >> 3;
    const int gid = blockIdx.x * 32 + wid * 8 + grp;  // entry 0..23039

    const int lev = gid / 7680;
    const int m = gid - lev * 7680;
    const int o = m / 1536;
    const int n = m - o * 1536;
    const int a = n >> 9;
    const int j = n & 511;

    const int gsz = (lev == 0) ? 52 : ((lev == 1) ? 26 : 13);
    const float* p = (lev == 0) ? p0 : ((lev == 1) ? p1 : p2);
    const int toff = (lev == 0) ? 0 : ((lev == 1) ? CELL0 : (CELL0 + CELL1));

    const float2 t01 = *(const float2*)(tgt + j * 6 + 0);
    const float2 t23 = *(const float2*)(tgt + j * 6 + 2);
    const float2 t45 = *(const float2*)(tgt + j * 6 + 4);
    const float img = t01.x, cls = t01.y;
    const float x1 = t23.x, y1 = t23.y, x2 = t45.x, y2 = t45.y;
    const float w = (float)gsz, h = (float)gsz;
    const float cx = (x1 + x2) * 0.5f, cy = (y1 + y2) * 0.5f;
    const float tw = x2 - x1, th = y2 - y1;
    const float gx = cx * w, gy = cy * h, gw = tw * w, gh = th * h;

    const float ax = c_anch[lev][a][0], ay = c_anch[lev][a][1];
    const float rx = gw / ax, ry = gh / ay;
    const float mr = fmaxf(fmaxf(rx, 1.0f / rx), fmaxf(ry, 1.0f / ry));
    bool valid = (mr < 4.0f);
    if (o == 1)
        valid = valid && (gx - floorf(gx) < 0.5f) && (gx > 1.0f);
    else if (o == 2)
        valid = valid && (gy - floorf(gy) < 0.5f) && (gy > 1.0f);
    else if (o == 3) {
        const float gxi = w - gx;
        valid = valid && (gxi - floorf(gxi) < 0.5f) && (gxi > 1.0f);
    } else if (o == 4) {
        const float gyi = h - gy;
        valid = valid && (gyi - floorf(gyi) < 0.5f) && (gyi > 1.0f);
    }

    float lbox_c = 0.f, cls_c = 0.f, cnt_c = 0.f;

    if (valid) {
        const float gijx = floorf(gx - c_offx[o]);
        const float gijy = floorf(gy - c_offy[o]);
        int gi = (int)gijx;
        gi = min(max(gi, 0), gsz - 1);
        int gj = (int)gijy;
        gj = min(max(gj, 0), gsz - 1);
        const int b = (int)img;
        const int c = (int)cls;
        const int cell = ((b * 3 + a) * gsz + gj) * gsz + gi;
        const long base = (long)cell * 85;

        float x0 = 0.f, s = 0.f;
#pragma unroll
        for (int k = 0; k < 11; ++k) {
            const int elem = g + 8 * k;
            if (elem < 85) {
                const float x = p[base + elem];
                if (k == 0) x0 = x;
                if (elem >= 5) s += bce(x, (elem - 5 == c) ? 0.95f : 0.05f);
            }
        }
        cls_c = s;

        const int gb = lane & 56;
        const float t0 = __shfl(x0, gb + 0);
        const float t1 = __shfl(x0, gb + 1);
        const float t2 = __shfl(x0, gb + 2);
        const float t3 = __shfl(x0, gb + 3);

        const float sx = 1.f / (1.f + expf(-t0));
        const float sy = 1.f / (1.f + expf(-t1));
        const float sw = 1.f / (1.f + expf(-t2));
        const float shh = 1.f / (1.f + expf(-t3));
        const float pxc = sx * 2.f - 0.5f;
        const float pyc = sy * 2.f - 0.5f;
        const float pw = (sw * 2.f) * (sw * 2.f) * ax;
        const float ph = (shh * 2.f) * (shh * 2.f) * ay;

        const float tbx = gx - gijx, tby = gy - gijy, tbw = gw, tbh = gh;

        const float b1x1 = pxc - pw * 0.5f, b1x2 = pxc + pw * 0.5f;
        const float b1y1 = pyc - ph * 0.5f, b1y2 = pyc + ph * 0.5f;
        const float b2x1 = tbx - tbw * 0.5f, b2x2 = tbx + tbw * 0.5f;
        const float b2y1 = tby - tbh * 0.5f, b2y2 = tby + tbh * 0.5f;
        float iw = fminf(b1x2, b2x2) - fmaxf(b1x1, b2x1);
        iw = fmaxf(iw, 0.f);
        float ih = fminf(b1y2, b2y2) - fmaxf(b1y1, b2y1);
        ih = fmaxf(ih, 0.f);
        const float inter = iw * ih;
        const float uni = pw * ph + tbw * tbh - inter + 1e-7f;
        const float iou = inter / uni;
        const float cw = fmaxf(b1x2, b2x2) - fminf(b1x1, b2x1);
        const float ch = fmaxf(b1y2, b2y2) - fminf(b1y1, b2y1);
        const float c2 = cw * cw + ch * ch + 1e-7f;
        const float dx = b2x1 + b2x2 - b1x1 - b1x2;
        const float dy = b2y1 + b2y2 - b1y1 - b1y2;
        const float rho2 = (dx * dx + dy * dy) * 0.25f;
        const float dv = atanf(tbw / tbh) - atanf(pw / ph);
        const float v = 0.40528473f * dv * dv;  // 4/pi^2
        const float alpha = v / (v - iou + 1.0000001f);
        const float ciou = iou - (rho2 / c2 + v * alpha);

        if (g == 0) {
            lbox_c = 1.f - ciou;
            cnt_c = 1.f;
            const float score = fmaxf(ciou, 0.f);
            if (score > 0.f) {
                unsigned int* tobj = (unsigned int*)(ws + TOBJ_OFF + toff);
                atomicMax(tobj + cell, __float_as_uint(score));
            }
        }
    }

    // ---- Phase B compute: named accumulators, no pointer-to-local ----
    float v0 = 0.f, v1 = 0.f, v2 = 0.f;
    {
        const float sa = softplus_bce0(xa);
        if (i0 < CELL0) v0 += sa;
        else if (i0 < CELL0 + CELL1) v1 += sa;
        else v2 += sa;
        if (hb) {
            const float sb2 = softplus_bce0(xbv);
            if (i1 < CELL0) v0 += sb2;
            else if (i1 < CELL0 + CELL1) v1 += sb2;
            else v2 += sb2;
        }
    }

    // wave-wide reduce of 6 values
#pragma unroll
    for (int msk = 1; msk < 64; msk <<= 1) {
        lbox_c += __shfl_xor(lbox_c, msk);
        cls_c += __shfl_xor(cls_c, msk);
        cnt_c += __shfl_xor(cnt_c, msk);
        v0 += __shfl_xor(v0, msk);
        v1 += __shfl_xor(v1, msk);
        v2 += __shfl_xor(v2, msk);
    }
    __shared__ float shred[4][6];
    if (lane == 0) {
        shred[wid][0] = lbox_c; shred[wid][1] = cls_c; shred[wid][2] = cnt_c;
        shred[wid][3] = v0; shred[wid][4] = v1; shred[wid][5] = v2;
    }
    __syncthreads();
    if (threadIdx.x == 0) {
        float* slot = ws + PART_OFF + blockIdx.x * 8;
#pragma unroll
        for (int q = 0; q < 6; ++q)
            slot[q] = shred[0][q] + shred[1][q] + shred[2][q] + shred[3][q];
    }
}

// 16 blocks: 4-way-unrolled float4 scan of tobj, gather x_obj for nonzero cells,
// xt = sum(x*t); last block (16 cheap counter atomics) reduces all partials.
__global__ __launch_bounds__(256) void k_corr_final(const float* __restrict__ p0,
                                                    const float* __restrict__ p1,
                                                    const float* __restrict__ p2,
                                                    float* __restrict__ ws,
                                                    float* __restrict__ out) {
    float xt0 = 0.f, xt1 = 0.f, xt2 = 0.f;
    const float4* tobj4 = (const float4*)(ws + TOBJ_OFF);
    const int tid = blockIdx.x * 256 + threadIdx.x;
    for (int base = 0; base < ZERO_F4; base += 4 * CORR_THREADS) {
#pragma unroll
        for (int u = 0; u < 4; ++u) {
            const int i = base + u * CORR_THREADS + tid;
            if (i < ZERO_F4) {
                const float4 t4 = tobj4[i];
                if (t4.x > 0.f || t4.y > 0.f || t4.z > 0.f || t4.w > 0.f) {
                    const int gb4 = 4 * i;  // one level per float4 group
                    const float* p;
                    int cb, lv;
                    if (gb4 < CELL0) { p = p0; cb = gb4; lv = 0; }
                    else if (gb4 < CELL0 + CELL1) { p = p1; cb = gb4 - CELL0; lv = 1; }
                    else { p = p2; cb = gb4 - (CELL0 + CELL1); lv = 2; }
                    float acc = 0.f;
                    if (t4.x > 0.f) acc += p[(long)(cb + 0) * 85 + 4] * t4.x;
                    if (t4.y > 0.f) acc += p[(long)(cb + 1) * 85 + 4] * t4.y;
                    if (t4.z > 0.f) acc += p[(long)(cb + 2) * 85 + 4] * t4.z;
                    if (t4.w > 0.f) acc += p[(long)(cb + 3) * 85 + 4] * t4.w;
                    if (lv == 0) xt0 += acc;
                    else if (lv == 1) xt1 += acc;
                    else xt2 += acc;
                }
            }
        }
    }
#pragma unroll
    for (int msk = 1; msk < 64; msk <<= 1) {
        xt0 += __shfl_xor(xt0, msk);
        xt1 += __shfl_xor(xt1, msk);
        xt2 += __shfl_xor(xt2, msk);
    }
    __shared__ float s0[4], s1[4], s2[4];
    const int wid = threadIdx.x >> 6, lane = threadIdx.x & 63;
    if (lane == 0) {
        s0[wid] = xt0; s1[wid] = xt1; s2[wid] = xt2;
    }
    __syncthreads();

    __shared__ unsigned int is_last;
    if (threadIdx.x == 0) {
        float* slot = ws + CORR_OFF + blockIdx.x * 4;
        slot[0] = s0[0] + s0[1] + s0[2] + s0[3];
        slot[1] = s1[0] + s1[1] + s1[2] + s1[3];
        slot[2] = s2[0] + s2[1] + s2[2] + s2[3];
        __threadfence();
        const unsigned int old = __hip_atomic_fetch_add(
            (unsigned int*)ws + CNT_IDX, 1u, __ATOMIC_ACQ_REL, __HIP_MEMORY_SCOPE_AGENT);
        is_last = (old == (unsigned int)(NCORR_BLOCKS - 1)) ? 1u : 0u;
    }
    __syncthreads();
    if (!is_last) return;

    // ---- final reduction ----
    // acc: [0..2]=lbox [3..5]=cls [6..8]=nvalid [9..11]=softplus-obj [12..14]=xt
    float acc[15];
#pragma unroll
    for (int q = 0; q < 15; ++q) acc[q] = 0.f;

    for (int i = threadIdx.x; i < NTGT_BLOCKS; i += 256) {
        const int lev = i / 240;
        const float* slot = ws + PART_OFF + i * 8;
        acc[lev] += slot[0];
        acc[3 + lev] += slot[1];
        acc[6 + lev] += slot[2];
        acc[9] += slot[3];
        acc[10] += slot[4];
        acc[11] += slot[5];
    }
    if (threadIdx.x < NCORR_BLOCKS) {
        const float* slot = ws + CORR_OFF + threadIdx.x * 4;
        acc[12] += slot[0];
        acc[13] += slot[1];
        acc[14] += slot[2];
    }
#pragma unroll
    for (int q = 0; q < 15; ++q)
        for (int msk = 32; msk; msk >>= 1) acc[q] += __shfl_xor(acc[q], msk);

    __shared__ float shf[4][15];
    if (lane == 0)
#pragma unroll
        for (int q = 0; q < 15; ++q) shf[wid][q] = acc[q];
    __syncthreads();

    if (threadIdx.x == 0) {
        float lbox = 0.f, lobj = 0.f, lcls = 0.f;
        const float bal[3] = {4.0f, 1.0f, 0.4f};
        const float ncell[3] = {(float)CELL0, (float)CELL1, (float)CELL2};
        for (int l = 0; l < 3; ++l) {
            const float sbv = shf[0][l] + shf[1][l] + shf[2][l] + shf[3][l];
            const float scv = shf[0][3 + l] + shf[1][3 + l] + shf[2][3 + l] + shf[3][3 + l];
            const float snv = shf[0][6 + l] + shf[1][6 + l] + shf[2][6 + l] + shf[3][6 + l];
            const float sov = shf[0][9 + l] + shf[1][9 + l] + shf[2][9 + l] + shf[3][9 + l];
            const float sxt = shf[0][12 + l] + shf[1][12 + l] + shf[2][12 + l] + shf[3][12 + l];
            const float nv = fmaxf(snv, 1.0f);
            lbox += sbv / nv;
            lcls += scv / (nv * (float)NCLS);
            lobj += (sov - sxt) / ncell[l] * bal[l];  // bce(x,t) = bce(x,0) - x*t
        }
        lbox *= 0.05f;
        lcls *= 0.5f;
        const float total = (lbox + lobj + lcls) * 32.0f;
        out[0] = total;
        out[1] = lbox;
        out[2] = lobj;
        out[3] = lcls;
    }
}

extern "C" void kernel_launch(void* const* d_in, const int* in_sizes, int n_in,
                              void* d_out, int out_size, void* d_ws, size_t ws_size,
                              hipStream_t stream) {
    const float* p0 = (const float*)d_in[0];
    const float* p1 = (const float*)d_in[1];
    const float* p2 = (const float*)d_in[2];
    const float* tgt = (const float*)d_in[3];
    float* ws = (float*)d_ws;
    float* out = (float*)d_out;

    k_zero<<<NZERO_BLOCKS, 256, 0, stream>>>(ws);
    k_targets_plus<<<NTGT_BLOCKS, 256, 0, stream>>>(p0, p1, p2, tgt, ws);
    k_corr_final<<<NCORR_BLOCKS, 256, 0, stream>>>(p0, p1, p2, ws, out);
}

// Round 7
// 52.041 us; speedup vs baseline: 1.5245x; 1.0061x over previous
//
#include <hip/hip_runtime.h>
#include <cmath>

#define NCLS 80

// cells per level: 32*3*g*g for g in {52,26,13}
#define CELL0 259584
#define CELL1 64896
#define CELL2 16224
#define CELLT (CELL0 + CELL1 + CELL2)   // 340704

#define NTGT_BLOCKS 720                 // 23040 entries / 32 entries per block
#define NOBJ_BLOCKS ((CELLT + 255) / 256)  // 1331
#define NCORR_BLOCKS 16
#define CORR_THREADS (NCORR_BLOCKS * 256)  // 4096

// ws float layout:
//  [0..15]                                   header: [12]=done-counter (uint)
//  [TOBJ_OFF .. +CELLT)                      tobj (zeroed by k_zero_obj)
//  [PART_OFF .. +NTGT_BLOCKS*4)              per-block {lbox, cls, nvalid, pad}
//  [OPART_OFF .. +NOBJ_BLOCKS*4)             per-block {sp0, sp1, sp2, pad}  (softplus sums)
//  [CORR_OFF .. +NCORR_BLOCKS*4)             per-block {xt0, xt1, xt2, pad}
#define TOBJ_OFF 16
#define PART_OFF (TOBJ_OFF + CELLT)
#define OPART_OFF (PART_OFF + NTGT_BLOCKS * 4)
#define CORR_OFF (OPART_OFF + NOBJ_BLOCKS * 4)
#define CNT_IDX 12

#define ZERO_F4 (CELLT / 4)             // 85176; level boundaries are /4-exact

__device__ __constant__ float c_anch[3][3][2] = {
    {{1.25f, 1.625f}, {2.0f, 3.75f}, {4.125f, 2.875f}},
    {{1.875f, 3.8125f}, {3.875f, 2.8125f}, {3.6875f, 7.4375f}},
    {{3.625f, 2.8125f}, {4.875f, 6.1875f}, {11.65625f, 10.1875f}}};
__device__ __constant__ float c_offx[5] = {0.f, 0.5f, 0.f, -0.5f, 0.f};
__device__ __constant__ float c_offy[5] = {0.f, 0.f, 0.5f, 0.f, -0.5f};

__device__ __forceinline__ float bce(float x, float y) {
    return fmaxf(x, 0.f) - x * y + log1pf(expf(-fabsf(x)));
}
__device__ __forceinline__ float softplus_bce0(float x) {  // bce(x, 0)
    return fmaxf(x, 0.f) + log1pf(expf(-fabsf(x)));
}

// Fused: zero tobj + header, AND tobj-independent softplus(obj) scan with per-block
// partials. 1331 blocks = 5324 waves all co-resident -> the 22 MB strided fetch is
// fully issued up front (BW-bound, not latency-bound).
__global__ __launch_bounds__(256) void k_zero_obj(const float* __restrict__ p0,
                                                  const float* __restrict__ p1,
                                                  const float* __restrict__ p2,
                                                  float* __restrict__ ws) {
    const int tid = blockIdx.x * 256 + threadIdx.x;

    // softplus load issued first (longest latency)
    float x = 0.f;
    const bool have = (tid < CELLT);
    if (have) {
        if (tid < CELL0) x = p0[(long)tid * 85 + 4];
        else if (tid < CELL0 + CELL1) x = p1[(long)(tid - CELL0) * 85 + 4];
        else x = p2[(long)(tid - (CELL0 + CELL1)) * 85 + 4];
    }

    // zero header + tobj
    if (tid < 16) ws[tid] = 0.f;
    if (tid < ZERO_F4) {
        float4 z;
        z.x = 0.f; z.y = 0.f; z.z = 0.f; z.w = 0.f;
        ((float4*)(ws + TOBJ_OFF))[tid] = z;
    }

    float v0 = 0.f, v1 = 0.f, v2 = 0.f;
    if (have) {
        const float sp = softplus_bce0(x);
        if (tid < CELL0) v0 = sp;
        else if (tid < CELL0 + CELL1) v1 = sp;
        else v2 = sp;
    }
#pragma unroll
    for (int msk = 1; msk < 64; msk <<= 1) {
        v0 += __shfl_xor(v0, msk);
        v1 += __shfl_xor(v1, msk);
        v2 += __shfl_xor(v2, msk);
    }
    __shared__ float s0[4], s1[4], s2[4];
    const int wid = threadIdx.x >> 6, lane = threadIdx.x & 63;
    if (lane == 0) { s0[wid] = v0; s1[wid] = v1; s2[wid] = v2; }
    __syncthreads();
    if (threadIdx.x == 0) {
        float* slot = ws + OPART_OFF + blockIdx.x * 4;
        slot[0] = s0[0] + s0[1] + s0[2] + s0[3];
        slot[1] = s1[0] + s1[1] + s1[2] + s1[3];
        slot[2] = s2[0] + s2[1] + s2[2] + s2[3];
    }
}

// 8-lane group per entry (8 entries/wave, 32/block, 720 blocks): box/cls/valid + tobj scatter.
__global__ __launch_bounds__(256) void k_targets(const float* __restrict__ p0,
                                                 const float* __restrict__ p1,
                                                 const float* __restrict__ p2,
                                                 const float* __restrict__ tgt,
                                                 float* __restrict__ ws) {
    const int lane = threadIdx.x & 63;
    const int wid = threadIdx.x >> 6;
    const int g = lane & 7;
    const int grp = lane >> 3;
    const int gid = blockIdx.x * 32 + wid * 8 + grp;  // entry 0..23039

    const int lev = gid / 7680;
    const int m = gid - lev * 7680;
    const int o = m / 1536;
    const int n = m - o * 1536;
    const int a = n >> 9;
    const int j = n & 511;

    const int gsz = (lev == 0) ? 52 : ((lev == 1) ? 26 : 13);
    const float* p = (lev == 0) ? p0 : ((lev == 1) ? p1 : p2);
    const int toff = (lev == 0) ? 0 : ((lev == 1) ? CELL0 : (CELL0 + CELL1));

    const float2 t01 = *(const float2*)(tgt + j * 6 + 0);
    const float2 t23 = *(const float2*)(tgt + j * 6 + 2);
    const float2 t45 = *(const float2*)(tgt + j * 6 + 4);
    const float img = t01.x, cls = t01.y;
    const float x1 = t23.x, y1 = t23.y, x2 = t45.x, y2 = t45.y;
    const float w = (float)gsz, h = (float)gsz;
    const float cx = (x1 + x2) * 0.5f, cy = (y1 + y2) * 0.5f;
    const float tw = x2 - x1, th = y2 - y1;
    const float gx = cx * w, gy = cy * h, gw = tw * w, gh = th * h;

    const float ax = c_anch[lev][a][0], ay = c_anch[lev][a][1];
    const float rx = gw / ax, ry = gh / ay;
    const float mr = fmaxf(fmaxf(rx, 1.0f / rx), fmaxf(ry, 1.0f / ry));
    bool valid = (mr < 4.0f);
    if (o == 1)
        valid = valid && (gx - floorf(gx) < 0.5f) && (gx > 1.0f);
    else if (o == 2)
        valid = valid && (gy - floorf(gy) < 0.5f) && (gy > 1.0f);
    else if (o == 3) {
        const float gxi = w - gx;
        valid = valid && (gxi - floorf(gxi) < 0.5f) && (gxi > 1.0f);
    } else if (o == 4) {
        const float gyi = h - gy;
        valid = valid && (gyi - floorf(gyi) < 0.5f) && (gyi > 1.0f);
    }

    float lbox_c = 0.f, cls_c = 0.f, cnt_c = 0.f;

    if (valid) {
        const float gijx = floorf(gx - c_offx[o]);
        const float gijy = floorf(gy - c_offy[o]);
        int gi = (int)gijx;
        gi = min(max(gi, 0), gsz - 1);
        int gj = (int)gijy;
        gj = min(max(gj, 0), gsz - 1);
        const int b = (int)img;
        const int c = (int)cls;
        const int cell = ((b * 3 + a) * gsz + gj) * gsz + gi;
        const long base = (long)cell * 85;

        float x0 = 0.f, s = 0.f;
#pragma unroll
        for (int k = 0; k < 11; ++k) {
            const int elem = g + 8 * k;
            if (elem < 85) {
                const float x = p[base + elem];
                if (k == 0) x0 = x;
                if (elem >= 5) s += bce(x, (elem - 5 == c) ? 0.95f : 0.05f);
            }
        }
        cls_c = s;

        const int gb = lane & 56;
        const float t0 = __shfl(x0, gb + 0);
        const float t1 = __shfl(x0, gb + 1);
        const float t2 = __shfl(x0, gb + 2);
        const float t3 = __shfl(x0, gb + 3);

        const float sx = 1.f / (1.f + expf(-t0));
        const float sy = 1.f / (1.f + expf(-t1));
        const float sw = 1.f / (1.f + expf(-t2));
        const float shh = 1.f / (1.f + expf(-t3));
        const float pxc = sx * 2.f - 0.5f;
        const float pyc = sy * 2.f - 0.5f;
        const float pw = (sw * 2.f) * (sw * 2.f) * ax;
        const float ph = (shh * 2.f) * (shh * 2.f) * ay;

        const float tbx = gx - gijx, tby = gy - gijy, tbw = gw, tbh = gh;

        const float b1x1 = pxc - pw * 0.5f, b1x2 = pxc + pw * 0.5f;
        const float b1y1 = pyc - ph * 0.5f, b1y2 = pyc + ph * 0.5f;
        const float b2x1 = tbx - tbw * 0.5f, b2x2 = tbx + tbw * 0.5f;
        const float b2y1 = tby - tbh * 0.5f, b2y2 = tby + tbh * 0.5f;
        float iw = fminf(b1x2, b2x2) - fmaxf(b1x1, b2x1);
        iw = fmaxf(iw, 0.f);
        float ih = fminf(b1y2, b2y2) - fmaxf(b1y1, b2y1);
        ih = fmaxf(ih, 0.f);
        const float inter = iw * ih;
        const float uni = pw * ph + tbw * tbh - inter + 1e-7f;
        const float iou = inter / uni;
        const float cw = fmaxf(b1x2, b2x2) - fminf(b1x1, b2x1);
        const float ch = fmaxf(b1y2, b2y2) - fminf(b1y1, b2y1);
        const float c2 = cw * cw + ch * ch + 1e-7f;
        const float dx = b2x1 + b2x2 - b1x1 - b1x2;
        const float dy = b2y1 + b2y2 - b1y1 - b1y2;
        const float rho2 = (dx * dx + dy * dy) * 0.25f;
        const float dv = atanf(tbw / tbh) - atanf(pw / ph);
        const float v = 0.40528473f * dv * dv;  // 4/pi^2
        const float alpha = v / (v - iou + 1.0000001f);
        const float ciou = iou - (rho2 / c2 + v * alpha);

        if (g == 0) {
            lbox_c = 1.f - ciou;
            cnt_c = 1.f;
            const float score = fmaxf(ciou, 0.f);
            if (score > 0.f) {
                unsigned int* tobj = (unsigned int*)(ws + TOBJ_OFF + toff);
                atomicMax(tobj + cell, __float_as_uint(score));
            }
        }
    }

#pragma unroll
    for (int msk = 1; msk < 64; msk <<= 1) {
        lbox_c += __shfl_xor(lbox_c, msk);
        cls_c += __shfl_xor(cls_c, msk);
        cnt_c += __shfl_xor(cnt_c, msk);
    }
    __shared__ float sb[4], sc[4], sn[4];
    if (lane == 0) { sb[wid] = lbox_c; sc[wid] = cls_c; sn[wid] = cnt_c; }
    __syncthreads();
    if (threadIdx.x == 0) {
        float* slot = ws + PART_OFF + blockIdx.x * 4;
        slot[0] = sb[0] + sb[1] + sb[2] + sb[3];
        slot[1] = sc[0] + sc[1] + sc[2] + sc[3];
        slot[2] = sn[0] + sn[1] + sn[2] + sn[3];
    }
}

// 16 blocks: 4-deep unrolled float4 scan of tobj; for nonzero cells gather x_obj and
// accumulate xt = sum(x*t); 16-block counter (cheap at this scale), final combine.
__global__ __launch_bounds__(256) void k_corr_final(const float* __restrict__ p0,
                                                    const float* __restrict__ p1,
                                                    const float* __restrict__ p2,
                                                    float* __restrict__ ws,
                                                    float* __restrict__ out) {
    float xt0 = 0.f, xt1 = 0.f, xt2 = 0.f;
    const float4* tobj4 = (const float4*)(ws + TOBJ_OFF);
    const int tid = blockIdx.x * 256 + threadIdx.x;
    for (int base = 0; base < ZERO_F4; base += 4 * CORR_THREADS) {
#pragma unroll
        for (int u = 0; u < 4; ++u) {
            const int i = base + u * CORR_THREADS + tid;
            if (i < ZERO_F4) {
                const float4 t4 = tobj4[i];
                if (t4.x > 0.f || t4.y > 0.f || t4.z > 0.f || t4.w > 0.f) {
                    const int gb4 = 4 * i;  // one level per float4 group
                    const float* p;
                    int cb, lv;
                    if (gb4 < CELL0) { p = p0; cb = gb4; lv = 0; }
                    else if (gb4 < CELL0 + CELL1) { p = p1; cb = gb4 - CELL0; lv = 1; }
                    else { p = p2; cb = gb4 - (CELL0 + CELL1); lv = 2; }
                    float acc = 0.f;
                    if (t4.x > 0.f) acc += p[(long)(cb + 0) * 85 + 4] * t4.x;
                    if (t4.y > 0.f) acc += p[(long)(cb + 1) * 85 + 4] * t4.y;
                    if (t4.z > 0.f) acc += p[(long)(cb + 2) * 85 + 4] * t4.z;
                    if (t4.w > 0.f) acc += p[(long)(cb + 3) * 85 + 4] * t4.w;
                    if (lv == 0) xt0 += acc;
                    else if (lv == 1) xt1 += acc;
                    else xt2 += acc;
                }
            }
        }
    }
#pragma unroll
    for (int msk = 1; msk < 64; msk <<= 1) {
        xt0 += __shfl_xor(xt0, msk);
        xt1 += __shfl_xor(xt1, msk);
        xt2 += __shfl_xor(xt2, msk);
    }
    __shared__ float s0[4], s1[4], s2[4];
    const int wid = threadIdx.x >> 6, lane = threadIdx.x & 63;
    if (lane == 0) { s0[wid] = xt0; s1[wid] = xt1; s2[wid] = xt2; }
    __syncthreads();

    __shared__ unsigned int is_last;
    if (threadIdx.x == 0) {
        float* slot = ws + CORR_OFF + blockIdx.x * 4;
        slot[0] = s0[0] + s0[1] + s0[2] + s0[3];
        slot[1] = s1[0] + s1[1] + s1[2] + s1[3];
        slot[2] = s2[0] + s2[1] + s2[2] + s2[3];
        __threadfence();
        const unsigned int old = __hip_atomic_fetch_add(
            (unsigned int*)ws + CNT_IDX, 1u, __ATOMIC_ACQ_REL, __HIP_MEMORY_SCOPE_AGENT);
        is_last = (old == (unsigned int)(NCORR_BLOCKS - 1)) ? 1u : 0u;
    }
    __syncthreads();
    if (!is_last) return;

    // acc: [0..2]=lbox [3..5]=cls [6..8]=nvalid [9..11]=softplus-obj [12..14]=xt
    float acc[15];
#pragma unroll
    for (int q = 0; q < 15; ++q) acc[q] = 0.f;

    for (int i = threadIdx.x; i < NTGT_BLOCKS; i += 256) {
        const int lev = i / 240;  // 240 k_targets blocks per level
        const float* slot = ws + PART_OFF + i * 4;
        acc[lev] += slot[0];
        acc[3 + lev] += slot[1];
        acc[6 + lev] += slot[2];
    }
    for (int i = threadIdx.x; i < NOBJ_BLOCKS; i += 256) {
        const float* slot = ws + OPART_OFF + i * 4;
        acc[9] += slot[0];
        acc[10] += slot[1];
        acc[11] += slot[2];
    }
    if (threadIdx.x < NCORR_BLOCKS) {
        const float* slot = ws + CORR_OFF + threadIdx.x * 4;
        acc[12] += slot[0];
        acc[13] += slot[1];
        acc[14] += slot[2];
    }
#pragma unroll
    for (int q = 0; q < 15; ++q)
        for (int msk = 32; msk; msk >>= 1) acc[q] += __shfl_xor(acc[q], msk);

    __shared__ float shf[4][15];
    if (lane == 0)
#pragma unroll
        for (int q = 0; q < 15; ++q) shf[wid][q] = acc[q];
    __syncthreads();

    if (threadIdx.x == 0) {
        float lbox = 0.f, lobj = 0.f, lcls = 0.f;
        const float bal[3] = {4.0f, 1.0f, 0.4f};
        const float ncell[3] = {(float)CELL0, (float)CELL1, (float)CELL2};
        for (int l = 0; l < 3; ++l) {
            const float sbv = shf[0][l] + shf[1][l] + shf[2][l] + shf[3][l];
            const float scv = shf[0][3 + l] + shf[1][3 + l] + shf[2][3 + l] + shf[3][3 + l];
            const float snv = shf[0][6 + l] + shf[1][6 + l] + shf[2][6 + l] + shf[3][6 + l];
            const float sov = shf[0][9 + l] + shf[1][9 + l] + shf[2][9 + l] + shf[3][9 + l];
            const float sxt = shf[0][12 + l] + shf[1][12 + l] + shf[2][12 + l] + shf[3][12 + l];
            const float nv = fmaxf(snv, 1.0f);
            lbox += sbv / nv;
            lcls += scv / (nv * (float)NCLS);
            lobj += (sov - sxt) / ncell[l] * bal[l];  // bce(x,t) = bce(x,0) - x*t
        }
        lbox *= 0.05f;
        lcls *= 0.5f;
        const float total = (lbox + lobj + lcls) * 32.0f;
        out[0] = total;
        out[1] = lbox;
        out[2] = lobj;
        out[3] = lcls;
    }
}

extern "C" void kernel_launch(void* const* d_in, const int* in_sizes, int n_in,
                              void* d_out, int out_size, void* d_ws, size_t ws_size,
                              hipStream_t stream) {
    const float* p0 = (const float*)d_in[0];
    const float* p1 = (const float*)d_in[1];
    const float* p2 = (const float*)d_in[2];
    const float* tgt = (const float*)d_in[3];
    float* ws = (float*)d_ws;
    float* out = (float*)d_out;

    k_zero_obj<<<NOBJ_BLOCKS, 256, 0, stream>>>(p0, p1, p2, ws);
    k_targets<<<NTGT_BLOCKS, 256, 0, stream>>>(p0, p1, p2, tgt, ws);
    k_corr_final<<<NCORR_BLOCKS, 256, 0, stream>>>(p0, p1, p2, ws, out);
}

// Round 8
// 34.165 us; speedup vs baseline: 2.3221x; 1.5232x over previous
//
#include <hip/hip_runtime.h>
#include <cmath>

#define NCLS 80

// cells per level: 32*3*g*g for g in {52,26,13}
#define CELL0 259584
#define CELL1 64896
#define CELL2 16224
#define CELLT (CELL0 + CELL1 + CELL2)   // 340704

#define NTGT_BLOCKS 720                 // 23040 entries / 32 entries per block (8-lane groups)
#define NOBJ_BLOCKS ((CELLT + 255) / 256)  // 1331

// ws float layout:
//  [TOBJ_OFF .. +CELLT)                      tobj (zeroed each call by k_zero)
//  [PART_OFF .. +NTGT_BLOCKS*4)              per-block {lbox, cls, nvalid, pad}
//  [OPART_OFF .. +NOBJ_BLOCKS*4)             per-block {obj0, obj1, obj2, pad}
#define TOBJ_OFF 16
#define PART_OFF (TOBJ_OFF + CELLT)
#define OPART_OFF (PART_OFF + NTGT_BLOCKS * 4)

#define ZERO_F4 (CELLT / 4)             // 85176 (CELLT % 4 == 0)
#define NZERO_BLOCKS ((ZERO_F4 + 255) / 256)

__device__ __constant__ float c_anch[3][3][2] = {
    {{1.25f, 1.625f}, {2.0f, 3.75f}, {4.125f, 2.875f}},
    {{1.875f, 3.8125f}, {3.875f, 2.8125f}, {3.6875f, 7.4375f}},
    {{3.625f, 2.8125f}, {4.875f, 6.1875f}, {11.65625f, 10.1875f}}};
__device__ __constant__ float c_offx[5] = {0.f, 0.5f, 0.f, -0.5f, 0.f};
__device__ __constant__ float c_offy[5] = {0.f, 0.f, 0.5f, 0.f, -0.5f};

__device__ __forceinline__ float bce(float x, float y) {
    return fmaxf(x, 0.f) - x * y + log1pf(expf(-fabsf(x)));
}

// Vectorized zero of tobj + header.
__global__ __launch_bounds__(256) void k_zero(float* __restrict__ ws) {
    const int i = blockIdx.x * 256 + threadIdx.x;
    if (blockIdx.x == 0 && threadIdx.x < 16) ws[threadIdx.x] = 0.f;
    if (i < ZERO_F4) {
        float4 z;
        z.x = 0.f; z.y = 0.f; z.z = 0.f; z.w = 0.f;
        ((float4*)(ws + TOBJ_OFF))[i] = z;
    }
}

// 8-lane group per entry (8 entries/wave, 32/block, 720 blocks): box/cls/valid + tobj scatter.
__global__ __launch_bounds__(256) void k_targets(const float* __restrict__ p0,
                                                 const float* __restrict__ p1,
                                                 const float* __restrict__ p2,
                                                 const float* __restrict__ tgt,
                                                 float* __restrict__ ws) {
    const int lane = threadIdx.x & 63;
    const int wid = threadIdx.x >> 6;
    const int g = lane & 7;
    const int grp = lane >> 3;
    const int gid = blockIdx.x * 32 + wid * 8 + grp;  // entry 0..23039

    const int lev = gid / 7680;
    const int m = gid - lev * 7680;
    const int o = m / 1536;
    const int n = m - o * 1536;
    const int a = n >> 9;
    const int j = n & 511;

    const int gsz = (lev == 0) ? 52 : ((lev == 1) ? 26 : 13);
    const float* p = (lev == 0) ? p0 : ((lev == 1) ? p1 : p2);
    const int toff = (lev == 0) ? 0 : ((lev == 1) ? CELL0 : (CELL0 + CELL1));

    const float2 t01 = *(const float2*)(tgt + j * 6 + 0);
    const float2 t23 = *(const float2*)(tgt + j * 6 + 2);
    const float2 t45 = *(const float2*)(tgt + j * 6 + 4);
    const float img = t01.x, cls = t01.y;
    const float x1 = t23.x, y1 = t23.y, x2 = t45.x, y2 = t45.y;
    const float w = (float)gsz, h = (float)gsz;
    const float cx = (x1 + x2) * 0.5f, cy = (y1 + y2) * 0.5f;
    const float tw = x2 - x1, th = y2 - y1;
    const float gx = cx * w, gy = cy * h, gw = tw * w, gh = th * h;

    const float ax = c_anch[lev][a][0], ay = c_anch[lev][a][1];
    const float rx = gw / ax, ry = gh / ay;
    const float mr = fmaxf(fmaxf(rx, 1.0f / rx), fmaxf(ry, 1.0f / ry));
    bool valid = (mr < 4.0f);
    if (o == 1)
        valid = valid && (gx - floorf(gx) < 0.5f) && (gx > 1.0f);
    else if (o == 2)
        valid = valid && (gy - floorf(gy) < 0.5f) && (gy > 1.0f);
    else if (o == 3) {
        const float gxi = w - gx;
        valid = valid && (gxi - floorf(gxi) < 0.5f) && (gxi > 1.0f);
    } else if (o == 4) {
        const float gyi = h - gy;
        valid = valid && (gyi - floorf(gyi) < 0.5f) && (gyi > 1.0f);
    }

    float lbox_c = 0.f, cls_c = 0.f, cnt_c = 0.f;

    if (valid) {
        const float gijx = floorf(gx - c_offx[o]);
        const float gijy = floorf(gy - c_offy[o]);
        int gi = (int)gijx;
        gi = min(max(gi, 0), gsz - 1);
        int gj = (int)gijy;
        gj = min(max(gj, 0), gsz - 1);
        const int b = (int)img;
        const int c = (int)cls;
        const int cell = ((b * 3 + a) * gsz + gj) * gsz + gi;
        const long base = (long)cell * 85;

        float x0 = 0.f, s = 0.f;
#pragma unroll
        for (int k = 0; k < 11; ++k) {
            const int elem = g + 8 * k;
            if (elem < 85) {
                const float x = p[base + elem];
                if (k == 0) x0 = x;
                if (elem >= 5) s += bce(x, (elem - 5 == c) ? 0.95f : 0.05f);
            }
        }
        cls_c = s;

        const int gb = lane & 56;
        const float t0 = __shfl(x0, gb + 0);
        const float t1 = __shfl(x0, gb + 1);
        const float t2 = __shfl(x0, gb + 2);
        const float t3 = __shfl(x0, gb + 3);

        const float sx = 1.f / (1.f + expf(-t0));
        const float sy = 1.f / (1.f + expf(-t1));
        const float sw = 1.f / (1.f + expf(-t2));
        const float shh = 1.f / (1.f + expf(-t3));
        const float pxc = sx * 2.f - 0.5f;
        const float pyc = sy * 2.f - 0.5f;
        const float pw = (sw * 2.f) * (sw * 2.f) * ax;
        const float ph = (shh * 2.f) * (shh * 2.f) * ay;

        const float tbx = gx - gijx, tby = gy - gijy, tbw = gw, tbh = gh;

        const float b1x1 = pxc - pw * 0.5f, b1x2 = pxc + pw * 0.5f;
        const float b1y1 = pyc - ph * 0.5f, b1y2 = pyc + ph * 0.5f;
        const float b2x1 = tbx - tbw * 0.5f, b2x2 = tbx + tbw * 0.5f;
        const float b2y1 = tby - tbh * 0.5f, b2y2 = tby + tbh * 0.5f;
        float iw = fminf(b1x2, b2x2) - fmaxf(b1x1, b2x1);
        iw = fmaxf(iw, 0.f);
        float ih = fminf(b1y2, b2y2) - fmaxf(b1y1, b2y1);
        ih = fmaxf(ih, 0.f);
        const float inter = iw * ih;
        const float uni = pw * ph + tbw * tbh - inter + 1e-7f;
        const float iou = inter / uni;
        const float cw = fmaxf(b1x2, b2x2) - fminf(b1x1, b2x1);
        const float ch = fmaxf(b1y2, b2y2) - fminf(b1y1, b2y1);
        const float c2 = cw * cw + ch * ch + 1e-7f;
        const float dx = b2x1 + b2x2 - b1x1 - b1x2;
        const float dy = b2y1 + b2y2 - b1y1 - b1y2;
        const float rho2 = (dx * dx + dy * dy) * 0.25f;
        const float dv = atanf(tbw / tbh) - atanf(pw / ph);
        const float v = 0.40528473f * dv * dv;  // 4/pi^2
        const float alpha = v / (v - iou + 1.0000001f);
        const float ciou = iou - (rho2 / c2 + v * alpha);

        if (g == 0) {
            lbox_c = 1.f - ciou;
            cnt_c = 1.f;
            const float score = fmaxf(ciou, 0.f);
            if (score > 0.f) {
                unsigned int* tobj = (unsigned int*)(ws + TOBJ_OFF + toff);
                atomicMax(tobj + cell, __float_as_uint(score));
            }
        }
    }

#pragma unroll
    for (int msk = 1; msk < 64; msk <<= 1) {
        lbox_c += __shfl_xor(lbox_c, msk);
        cls_c += __shfl_xor(cls_c, msk);
        cnt_c += __shfl_xor(cnt_c, msk);
    }
    __shared__ float sb[4], sc[4], sn[4];
    if (lane == 0) { sb[wid] = lbox_c; sc[wid] = cls_c; sn[wid] = cnt_c; }
    __syncthreads();
    if (threadIdx.x == 0) {
        float* slot = ws + PART_OFF + blockIdx.x * 4;
        slot[0] = sb[0] + sb[1] + sb[2] + sb[3];
        slot[1] = sc[0] + sc[1] + sc[2] + sc[3];
        slot[2] = sn[0] + sn[1] + sn[2] + sn[3];
    }
}

// One thread per cell: strided read of obj channel + coalesced tobj, bce, per-block partials.
// Single pass (R3 structure — the fastest measured).
__global__ __launch_bounds__(256) void k_obj(const float* __restrict__ p0,
                                             const float* __restrict__ p1,
                                             const float* __restrict__ p2,
                                             float* __restrict__ ws) {
    const int idx = blockIdx.x * 256 + threadIdx.x;
    float v0 = 0.f, v1 = 0.f, v2 = 0.f;
    if (idx < CELLT) {
        float x, t;
        int lev;
        if (idx < CELL0) {
            lev = 0;
            x = p0[(long)idx * 85 + 4];
            t = ws[TOBJ_OFF + idx];
        } else if (idx < CELL0 + CELL1) {
            lev = 1;
            x = p1[(long)(idx - CELL0) * 85 + 4];
            t = ws[TOBJ_OFF + idx];
        } else {
            lev = 2;
            x = p2[(long)(idx - (CELL0 + CELL1)) * 85 + 4];
            t = ws[TOBJ_OFF + idx];
        }
        const float b = fmaxf(x, 0.f) - x * t + log1pf(expf(-fabsf(x)));
        if (lev == 0) v0 = b;
        else if (lev == 1) v1 = b;
        else v2 = b;
    }
#pragma unroll
    for (int msk = 32; msk; msk >>= 1) {
        v0 += __shfl_xor(v0, msk);
        v1 += __shfl_xor(v1, msk);
        v2 += __shfl_xor(v2, msk);
    }
    __shared__ float s0[4], s1[4], s2[4];
    const int wid = threadIdx.x >> 6, lane = threadIdx.x & 63;
    if (lane == 0) { s0[wid] = v0; s1[wid] = v1; s2[wid] = v2; }
    __syncthreads();
    if (threadIdx.x == 0) {
        float* slot = ws + OPART_OFF + blockIdx.x * 4;
        slot[0] = s0[0] + s0[1] + s0[2] + s0[3];
        slot[1] = s1[0] + s1[1] + s1[2] + s1[3];
        slot[2] = s2[0] + s2[1] + s2[2] + s2[3];
    }
}

// Single 256-thread block: deterministic reduction of all partials + final combine.
__global__ __launch_bounds__(256) void k_final(const float* __restrict__ ws,
                                               float* __restrict__ out) {
    float acc[12];
#pragma unroll
    for (int q = 0; q < 12; ++q) acc[q] = 0.f;

    for (int i = threadIdx.x; i < NTGT_BLOCKS; i += 256) {
        const int lev = i / 240;  // 240 k_targets blocks per level
        const float* slot = ws + PART_OFF + i * 4;
        acc[lev] += slot[0];
        acc[3 + lev] += slot[1];
        acc[6 + lev] += slot[2];
    }
    for (int i = threadIdx.x; i < NOBJ_BLOCKS; i += 256) {
        const float* slot = ws + OPART_OFF + i * 4;
        acc[9] += slot[0];
        acc[10] += slot[1];
        acc[11] += slot[2];
    }
#pragma unroll
    for (int q = 0; q < 12; ++q)
        for (int msk = 32; msk; msk >>= 1) acc[q] += __shfl_xor(acc[q], msk);

    __shared__ float sh[4][12];
    const int wid = threadIdx.x >> 6, lane = threadIdx.x & 63;
    if (lane == 0)
#pragma unroll
        for (int q = 0; q < 12; ++q) sh[wid][q] = acc[q];
    __syncthreads();

    if (threadIdx.x == 0) {
        float lbox = 0.f, lobj = 0.f, lcls = 0.f;
        const float bal[3] = {4.0f, 1.0f, 0.4f};
        const float ncell[3] = {(float)CELL0, (float)CELL1, (float)CELL2};
        for (int l = 0; l < 3; ++l) {
            const float sbv = sh[0][l] + sh[1][l] + sh[2][l] + sh[3][l];
            const float scv = sh[0][3 + l] + sh[1][3 + l] + sh[2][3 + l] + sh[3][3 + l];
            const float snv = sh[0][6 + l] + sh[1][6 + l] + sh[2][6 + l] + sh[3][6 + l];
            const float sov = sh[0][9 + l] + sh[1][9 + l] + sh[2][9 + l] + sh[3][9 + l];
            const float nv = fmaxf(snv, 1.0f);
            lbox += sbv / nv;
            lcls += scv / (nv * (float)NCLS);
            lobj += sov / ncell[l] * bal[l];
        }
        lbox *= 0.05f;
        lcls *= 0.5f;
        const float total = (lbox + lobj + lcls) * 32.0f;
        out[0] = total;
        out[1] = lbox;
        out[2] = lobj;
        out[3] = lcls;
    }
}

extern "C" void kernel_launch(void* const* d_in, const int* in_sizes, int n_in,
                              void* d_out, int out_size, void* d_ws, size_t ws_size,
                              hipStream_t stream) {
    const float* p0 = (const float*)d_in[0];
    const float* p1 = (const float*)d_in[1];
    const float* p2 = (const float*)d_in[2];
    const float* tgt = (const float*)d_in[3];
    float* ws = (float*)d_ws;
    float* out = (float*)d_out;

    k_zero<<<NZERO_BLOCKS, 256, 0, stream>>>(ws);
    k_targets<<<NTGT_BLOCKS, 256, 0, stream>>>(p0, p1, p2, tgt, ws);
    k_obj<<<NOBJ_BLOCKS, 256, 0, stream>>>(p0, p1, p2, ws);
    k_final<<<1, 256, 0, stream>>>(ws, out);
}